// Round 3
// baseline (139.027 us; speedup 1.0000x reference)
//
#include <hip/hip_runtime.h>

// FAVOR+ causal linear attention, fp32 I/O, bf16 MFMA chunked-GEMM form.
// B=2, L=4096, H=8, D=64, M=128, chunks C=64 x T=64.
// Occupancy-first split (phase-1 was latency-bound at 2 blocks/CU):
//   k0:  P fp32 -> bf16 once.
//   k1a: features Qf,Kf = relu(ratio*X P^T)+eps -> global ([t][m] dense,
//        packed 8B stores from MFMA regs); cs = (V^T Kf, colsum Kf).
//        LDS = Vt + Kft only, XOR-swizzled (no pads): 24.5 KB -> 6 blocks/CU.
//   k2:  exclusive bf16 prefix over chunks per (b,h).
//   k3': S = mask(Qf Kf^T); num2 = S V; num1 = Qf*KVpre; den = Qf.kspre + rs;
//        out = (num1+num2)/den. Qf/Kf/cs read as frags DIRECT from global
//        (L2/L3-resident); LDS = Vt + Sm = 16.5 KB -> 9+ blocks/CU.
//        n2 global round-trip eliminated; rs stays in registers.

#define B_ 2
#define L_ 4096
#define H_ 8
#define D_ 64
#define M_ 128
#define BH_ 16
#define HD_ 512
#define LHD_ (L_*HD_)
#define C_ 64
#define T_ 64
#define RATIO 0.08838834764831845f
#define EPS 1e-3f

#define REC_CS 8320                    // shorts per cs record: 64*128 KVt + 128 ks
#define REC_F  8192                    // shorts per Qf/Kf record: 64*128
#define QF_OFF 8519680                 // shorts: 16*64*8320
#define KF_OFF 16908288                // shorts: QF_OFF + 16*64*8192
#define P_OFF  25296896                // shorts: KF_OFF + 16*64*8192; P bf16 [m][d]

// XOR-swizzled LDS addressing for [row][col] short tiles with 64-short rows:
// short index = row*64 + (col ^ ((row&7)*8)); keeps 16B alignment for col%8==0.
#define SWZ(r,c) ((r)*64 + ((c) ^ (((r)&7)*8)))

typedef __attribute__((ext_vector_type(8))) short bf16x8;
typedef __attribute__((ext_vector_type(4))) short bf16x4;
typedef __attribute__((ext_vector_type(4))) float f32x4;

__device__ __forceinline__ short f2bf(float f) {
  union { float f; unsigned u; } x; x.f = f;
  unsigned r = (x.u + 0x7fffu + ((x.u >> 16) & 1u)) >> 16;
  return (short)r;
}
__device__ __forceinline__ float bf2f(short s) {
  union { unsigned u; float f; } x; x.u = ((unsigned)(unsigned short)s) << 16;
  return x.f;
}
__device__ __forceinline__ bf16x8 cvt8(float4 a, float4 b) {
  union { bf16x8 v; short s[8]; } u;
  u.s[0]=f2bf(a.x); u.s[1]=f2bf(a.y); u.s[2]=f2bf(a.z); u.s[3]=f2bf(a.w);
  u.s[4]=f2bf(b.x); u.s[5]=f2bf(b.y); u.s[6]=f2bf(b.z); u.s[7]=f2bf(b.w);
  return u.v;
}
#define MFMA(a,b,c) __builtin_amdgcn_mfma_f32_16x16x32_bf16((a),(b),(c),0,0,0)

// ---------------- k0: P -> bf16 once ----------------------------------------
__global__ __launch_bounds__(256) void k0(
    const float* __restrict__ P, unsigned short* __restrict__ ws)
{
  const int i = (blockIdx.x*256 + threadIdx.x)*4;   // 8 blocks * 256 * 4 = 8192
  float4 p4 = *(const float4*)(P + i);
  union { bf16x4 v; short s[4]; } u;
  u.s[0]=f2bf(p4.x); u.s[1]=f2bf(p4.y); u.s[2]=f2bf(p4.z); u.s[3]=f2bf(p4.w);
  *(bf16x4*)(ws + P_OFF + i) = u.v;
}

// ---------------- k1a: features + cs ----------------------------------------
__global__ __launch_bounds__(256) void k1a(
    const float* __restrict__ qq, const float* __restrict__ kk,
    const float* __restrict__ vv, unsigned short* __restrict__ ws)
{
  __shared__ short Vt[64*64];        // [d][t], swizzled
  __shared__ short Kft[128*64];      // [m][t], swizzled

  const int tid = threadIdx.x, bid = blockIdx.x;
  const int bh = bid >> 6, c = bid & 63;
  const int b = bh >> 3, h = bh & 7;
  const int lane = tid & 63, w = tid >> 6, quad = lane >> 4, l15 = lane & 15;
  const size_t gbase = (size_t)b*LHD_ + (size_t)h*D_;
  const int t0 = c*T_;
  const unsigned short* Pb = ws + P_OFF;

  // issue q/k row loads first (latency overlaps Vt staging)
  const float* qrow = qq + gbase + (size_t)(t0 + 16*w + l15)*HD_;
  const float* krow = kk + gbase + (size_t)(t0 + 16*w + l15)*HD_;
  float4 q4a = *(const float4*)(qrow + quad*8);
  float4 q4b = *(const float4*)(qrow + quad*8 + 4);
  float4 q4c = *(const float4*)(qrow + 32 + quad*8);
  float4 q4d = *(const float4*)(qrow + 32 + quad*8 + 4);
  float4 k4a = *(const float4*)(krow + quad*8);
  float4 k4b = *(const float4*)(krow + quad*8 + 4);
  float4 k4c = *(const float4*)(krow + 32 + quad*8);
  float4 k4d = *(const float4*)(krow + 32 + quad*8 + 4);

  // stage Vt[d][t] (transpose, swizzled)
  for (int fi = tid; fi < 64*16; fi += 256) {
    int t = fi >> 4, d4 = (fi & 15)*4;
    float4 v4 = *(const float4*)(vv + gbase + (size_t)(t0+t)*HD_ + d4);
    Vt[SWZ(d4+0, t)] = f2bf(v4.x);
    Vt[SWZ(d4+1, t)] = f2bf(v4.y);
    Vt[SWZ(d4+2, t)] = f2bf(v4.z);
    Vt[SWZ(d4+3, t)] = f2bf(v4.w);
  }

  bf16x8 bq0 = cvt8(q4a, q4b), bq1 = cvt8(q4c, q4d);
  bf16x8 bk0 = cvt8(k4a, k4b), bk1 = cvt8(k4c, k4d);

  unsigned short* qfb = ws + QF_OFF + (size_t)(bh*C_+c)*REC_F;
  unsigned short* kfb = ws + KF_OFF + (size_t)(bh*C_+c)*REC_F;
  const int trow = 16*w + l15;

  // features, swapped operands: D[m][t] -> lane holds t=trow, m=16ct+4quad+reg
  #pragma unroll
  for (int ct = 0; ct < 8; ++ct) {
    bf16x8 ap0 = *(const bf16x8*)(Pb + (ct*16 + l15)*64 + quad*8);
    bf16x8 ap1 = *(const bf16x8*)(Pb + (ct*16 + l15)*64 + 32 + quad*8);
    f32x4 qa = {0.f,0.f,0.f,0.f}, ka = {0.f,0.f,0.f,0.f};
    qa = MFMA(ap0,bq0,qa); qa = MFMA(ap1,bq1,qa);
    ka = MFMA(ap0,bk0,ka); ka = MFMA(ap1,bk1,ka);
    union { bf16x4 v; short s[4]; } pq, pk;
    #pragma unroll
    for (int reg = 0; reg < 4; ++reg) {
      int m = 16*ct + 4*quad + reg;
      short qv = f2bf(fmaxf(qa[reg]*RATIO, 0.f) + EPS);
      short kv = f2bf(fmaxf(ka[reg]*RATIO, 0.f) + EPS);
      pq.s[reg] = qv; pk.s[reg] = kv;
      Kft[SWZ(m, trow)] = kv;
    }
    *(bf16x4*)(qfb + trow*128 + 16*ct + 4*quad) = pq.v;
    *(bf16x4*)(kfb + trow*128 + 16*ct + 4*quad) = pk.v;
  }
  __syncthreads();  // Vt, Kft complete

  unsigned short* csb = ws + (size_t)(bh*C_+c)*REC_CS;

  // ks[m] = sum_t Kf[t][m]
  if (tid < 128) {
    float s = 0.f;
    #pragma unroll
    for (int i = 0; i < 8; ++i) {
      bf16x8 r = *(const bf16x8*)&Kft[SWZ(tid, 8*i)];
      #pragma unroll
      for (int j = 0; j < 8; ++j) s += bf2f(r[j]);
    }
    csb[64*128 + tid] = (unsigned short)f2bf(s);
  }

  // KV^T: cs[d][m] = sum_t Kf[t][m] V[t][d]; packed 8B stores
  {
    bf16x8 av0 = *(const bf16x8*)&Vt[SWZ(trow, quad*8)];
    bf16x8 av1 = *(const bf16x8*)&Vt[SWZ(trow, 32 + quad*8)];
    #pragma unroll
    for (int mt = 0; mt < 8; ++mt) {
      bf16x8 b0 = *(const bf16x8*)&Kft[SWZ(16*mt + l15, quad*8)];
      bf16x8 b1 = *(const bf16x8*)&Kft[SWZ(16*mt + l15, 32 + quad*8)];
      f32x4 acc = {0.f,0.f,0.f,0.f};
      acc = MFMA(b0, av0, acc);
      acc = MFMA(b1, av1, acc);
      union { bf16x4 v; short s[4]; } pc;
      #pragma unroll
      for (int reg = 0; reg < 4; ++reg) pc.s[reg] = f2bf(acc[reg]);
      *(bf16x4*)(csb + trow*128 + 16*mt + 4*quad) = pc.v;
    }
  }
}

// ---------------- k2: bf16 exclusive prefix, width-1, full prefetch ---------
__global__ __launch_bounds__(256) void k2(unsigned short* __restrict__ ws)
{
  const int gid = blockIdx.x*256 + threadIdx.x;   // 520*256 = 16*8320 exactly
  const int bh = gid / REC_CS, e = gid % REC_CS;
  unsigned short* base = ws + (size_t)bh*C_*REC_CS + e;
  short v[64];
  #pragma unroll
  for (int c2 = 0; c2 < 64; ++c2) v[c2] = (short)base[(size_t)c2*REC_CS];
  float run = 0.f;
  #pragma unroll
  for (int c2 = 0; c2 < 64; ++c2) {
    base[(size_t)c2*REC_CS] = (unsigned short)f2bf(run);
    run += bf2f(v[c2]);
  }
}

// ---------------- k3: S + num2 + num1 + den + combine -----------------------
__global__ __launch_bounds__(256) void k3(
    const float* __restrict__ vv, const unsigned short* __restrict__ ws,
    float* __restrict__ out)
{
  __shared__ short Vt[64*64];        // [d][t], swizzled
  __shared__ short Sm[64*64];        // [i][j], swizzled

  const int tid = threadIdx.x, bid = blockIdx.x;
  const int bh = bid >> 6, c = bid & 63;
  const int b = bh >> 3, h = bh & 7;
  const int lane = tid & 63, w = tid >> 6, quad = lane >> 4, l15 = lane & 15;
  const size_t gbase = (size_t)b*LHD_ + (size_t)h*D_;
  const int t0 = c*T_;
  const unsigned short* csb = ws + (size_t)(bh*C_+c)*REC_CS;
  const unsigned short* qfb = ws + QF_OFF + (size_t)(bh*C_+c)*REC_F;
  const unsigned short* kfb = ws + KF_OFF + (size_t)(bh*C_+c)*REC_F;
  const int trow = 16*w + l15;
  const int tg = t0 + trow;

  // stage Vt[d][t] (transpose, swizzled)
  for (int fi = tid; fi < 64*16; fi += 256) {
    int t = fi >> 4, d4 = (fi & 15)*4;
    float4 v4 = *(const float4*)(vv + gbase + (size_t)(t0+t)*HD_ + d4);
    Vt[SWZ(d4+0, t)] = f2bf(v4.x);
    Vt[SWZ(d4+1, t)] = f2bf(v4.y);
    Vt[SWZ(d4+2, t)] = f2bf(v4.z);
    Vt[SWZ(d4+3, t)] = f2bf(v4.w);
  }

  // Qf frags (rows t=trow; used as A for S and as B for num1) + prefixed ks
  bf16x8 qfB[4], ksf[4];
  #pragma unroll
  for (int ks2 = 0; ks2 < 4; ++ks2) {
    qfB[ks2] = *(const bf16x8*)(qfb + trow*128 + ks2*32 + quad*8);
    ksf[ks2] = *(const bf16x8*)(csb + 64*128 + ks2*32 + quad*8);
  }
  // den1 = Qf . ks_prefix (per-lane partial over 32 m, reduce across quads)
  float dp = 0.f;
  #pragma unroll
  for (int ks2 = 0; ks2 < 4; ++ks2)
    #pragma unroll
    for (int j = 0; j < 8; ++j) dp += bf2f(qfB[ks2][j]) * bf2f(ksf[ks2][j]);
  dp += __shfl_xor(dp, 16);
  dp += __shfl_xor(dp, 32);

  // S = mask(Qf Kf^T): D[t][j], A=Qf regs, B=Kf frags direct from global
  f32x4 sacc[4];
  #pragma unroll
  for (int jt = 0; jt < 4; ++jt) { f32x4 z = {0.f,0.f,0.f,0.f}; sacc[jt] = z; }
  #pragma unroll
  for (int ks2 = 0; ks2 < 4; ++ks2) {
    #pragma unroll
    for (int jt = 0; jt < 4; ++jt) {
      bf16x8 bb = *(const bf16x8*)(kfb + (16*jt + l15)*128 + ks2*32 + quad*8);
      sacc[jt] = MFMA(qfB[ks2], bb, sacc[jt]);
    }
  }
  __syncthreads();  // Vt staging complete (placed late to overlap)

  float rs[4] = {0.f,0.f,0.f,0.f};
  #pragma unroll
  for (int jt = 0; jt < 4; ++jt)
    #pragma unroll
    for (int reg = 0; reg < 4; ++reg) {
      int row = 16*w + 4*quad + reg;
      int j = l15 + 16*jt;
      float val = (j <= row) ? sacc[jt][reg] : 0.f;
      rs[reg] += val;
      Sm[SWZ(row, j)] = f2bf(val);
    }
  #pragma unroll
  for (int reg = 0; reg < 4; ++reg) {
    rs[reg] += __shfl_xor(rs[reg], 1);
    rs[reg] += __shfl_xor(rs[reg], 2);
    rs[reg] += __shfl_xor(rs[reg], 4);
    rs[reg] += __shfl_xor(rs[reg], 8);
  }
  // den for row trow: den1(dp broadcast) + rs; rs for row trow lives on
  // quad-0..3 lanes as rs[reg] with row=16w+4quad+reg -> shuffle to row-owner
  float rsv_ = (l15 < 4) ? ((l15==0)?rs[0]:(l15==1)?rs[1]:(l15==2)?rs[2]:rs[3]) : 0.f;
  // lane holding row r=16w+4q+reg is (quad=q, l15=reg); row-owner lane (quad', l15=r&15)
  // broadcast via LDS-free shuffle: each lane fetches from lane 16*( (l15>>2) ) + (l15&3)
  float rsv = __shfl(rsv_, ((l15 >> 2) << 4) + (l15 & 3), 64);
  float inv = 1.f / (dp + rsv);

  // num2 = S V as D[d][t]: A=Vt rows d, B=Sm rows t (same-wave rows, no barrier)
  f32x4 macc[4];
  #pragma unroll
  for (int ct = 0; ct < 4; ++ct) { f32x4 z = {0.f,0.f,0.f,0.f}; macc[ct] = z; }
  #pragma unroll
  for (int kss = 0; kss < 2; ++kss) {
    bf16x8 sb = *(const bf16x8*)&Sm[SWZ(trow, kss*32 + quad*8)];
    #pragma unroll
    for (int ct = 0; ct < 4; ++ct) {
      bf16x8 a = *(const bf16x8*)&Vt[SWZ(16*ct + l15, kss*32 + quad*8)];
      macc[ct] = MFMA(a, sb, macc[ct]);
    }
  }

  // num1 = Qf * KVpre as D[d][t]: A=cs rows d, B=Qf rows t
  f32x4 nacc[4];
  #pragma unroll
  for (int ct = 0; ct < 4; ++ct) { f32x4 z = {0.f,0.f,0.f,0.f}; nacc[ct] = z; }
  #pragma unroll
  for (int ks2 = 0; ks2 < 4; ++ks2) {
    #pragma unroll
    for (int ct = 0; ct < 4; ++ct) {
      bf16x8 a = *(const bf16x8*)(csb + (16*ct + l15)*128 + ks2*32 + quad*8);
      nacc[ct] = MFMA(a, qfB[ks2], nacc[ct]);
    }
  }
  #pragma unroll
  for (int ct = 0; ct < 4; ++ct) {
    float4 o;
    o.x = (nacc[ct][0] + macc[ct][0]) * inv;
    o.y = (nacc[ct][1] + macc[ct][1]) * inv;
    o.z = (nacc[ct][2] + macc[ct][2]) * inv;
    o.w = (nacc[ct][3] + macc[ct][3]) * inv;
    *(float4*)(out + gbase + (size_t)tg*HD_ + 16*ct + 4*quad) = o;
  }
}

extern "C" void kernel_launch(void* const* d_in, const int* in_sizes, int n_in,
                              void* d_out, int out_size, void* d_ws, size_t ws_size,
                              hipStream_t stream) {
  const float* q = (const float*)d_in[0];
  const float* k = (const float*)d_in[1];
  const float* v = (const float*)d_in[2];
  const float* P = (const float*)d_in[3];
  float* out = (float*)d_out;
  unsigned short* ws = (unsigned short*)d_ws;  // needs ~50.6 MB

  dim3 blk(256);
  k0<<<dim3(8), blk, 0, stream>>>(P, ws);
  k1a<<<dim3(BH_*C_), blk, 0, stream>>>(q, k, v, ws);
  k2<<<dim3(520), blk, 0, stream>>>(ws);
  k3<<<dim3(BH_*C_), blk, 0, stream>>>(v, ws, out);
}

// Round 4
// 128.392 us; speedup vs baseline: 1.0828x; 1.0828x over previous
//
#include <hip/hip_runtime.h>

// FAVOR+ causal linear attention, fp32 I/O, bf16 MFMA chunked-GEMM form.
// B=2, L=4096, H=8, D=64, M=128, chunks C=64 x T=64.
// R4 structure (back to R2's fat-k1, occupancy-fixed):
//   k0: P fp32 -> bf16 once.
//   k1: features Qf,Kf; cs = (V^T Kf, colsum Kf); S = mask(Qf Kf^T);
//       num2 = S V -> n2 (f32); rs = rowsum(S). Qf -> global direct from
//       MFMA regs (8B packs). Qf A-frags via same-wave 8KB scratch (2-pass,
//       barrier-free) -> QfTM eliminated. LDS 48KB -> 3 blocks/CU.
//   k2: exclusive bf16 prefix; 520 blocks x 64 thr, bf16x4 full prefetch.
//   k3: num1 = Qf*KVpre + combine. cs STAGED in LDS once (was read 4x
//       redundantly from global by each wave in R3 -> the 6us regression).

#define B_ 2
#define L_ 4096
#define H_ 8
#define D_ 64
#define M_ 128
#define BH_ 16
#define HD_ 512
#define LHD_ (L_*HD_)
#define C_ 64
#define T_ 64
#define RATIO 0.08838834764831845f
#define EPS 1e-3f

#define REC_CS 8320                    // shorts per cs record: 64*128 KVt + 128 ks
#define REC_F  8192                    // shorts per Qf record: 64*128
#define QF_OFF 8519680                 // shorts: 16*64*8320
#define N2_OFF 16908288                // shorts: QF_OFF + 16*64*8192 (f32 region)
#define RS_OFF 25296896                // shorts: N2_OFF + 2*4194304   (f32 region)
#define P_OFF  25427968                // shorts: RS_OFF + 131072; P bf16 [m][d]

// XOR-swizzles (bank-conflict-free, keep 8-short groups contiguous):
#define SWZ64(r,c)  ((r)*64  + ((c) ^ (((r)&7)*8)))
#define SWZ128(r,c) ((r)*128 + ((c) ^ (((r)&15)*8)))

typedef __attribute__((ext_vector_type(8))) short bf16x8;
typedef __attribute__((ext_vector_type(4))) short bf16x4;
typedef __attribute__((ext_vector_type(4))) float f32x4;

__device__ __forceinline__ short f2bf(float f) {
  union { float f; unsigned u; } x; x.f = f;
  unsigned r = (x.u + 0x7fffu + ((x.u >> 16) & 1u)) >> 16;
  return (short)r;
}
__device__ __forceinline__ float bf2f(short s) {
  union { unsigned u; float f; } x; x.u = ((unsigned)(unsigned short)s) << 16;
  return x.f;
}
__device__ __forceinline__ bf16x8 cvt8(float4 a, float4 b) {
  union { bf16x8 v; short s[8]; } u;
  u.s[0]=f2bf(a.x); u.s[1]=f2bf(a.y); u.s[2]=f2bf(a.z); u.s[3]=f2bf(a.w);
  u.s[4]=f2bf(b.x); u.s[5]=f2bf(b.y); u.s[6]=f2bf(b.z); u.s[7]=f2bf(b.w);
  return u.v;
}
#define MFMA(a,b,c) __builtin_amdgcn_mfma_f32_16x16x32_bf16((a),(b),(c),0,0,0)

// ---------------- k0: P -> bf16 once ----------------------------------------
__global__ __launch_bounds__(256) void k0(
    const float* __restrict__ P, unsigned short* __restrict__ ws)
{
  const int i = (blockIdx.x*256 + threadIdx.x)*4;   // 8 blocks * 256 * 4 = 8192
  float4 p4 = *(const float4*)(P + i);
  union { bf16x4 v; short s[4]; } u;
  u.s[0]=f2bf(p4.x); u.s[1]=f2bf(p4.y); u.s[2]=f2bf(p4.z); u.s[3]=f2bf(p4.w);
  *(bf16x4*)(ws + P_OFF + i) = u.v;
}

// ---------------- k1: all intra-chunk work ----------------------------------
__global__ __launch_bounds__(256) void k1(
    const float* __restrict__ qq, const float* __restrict__ kk,
    const float* __restrict__ vv, unsigned short* __restrict__ ws)
{
  __shared__ short Vt[64*64];        // [d][t], SWZ64
  __shared__ short Kft[128*64];      // [m][t], SWZ64
  __shared__ short KfTM[64*128];     // [t][m], SWZ128
  __shared__ short Scr[64*64];       // per-wave Qf extraction scratch; later Sm

  const int tid = threadIdx.x, bid = blockIdx.x;
  const int bh = bid >> 6, c = bid & 63;
  const int b = bh >> 3, h = bh & 7;
  const int lane = tid & 63, w = tid >> 6, quad = lane >> 4, l15 = lane & 15;
  const size_t gbase = (size_t)b*LHD_ + (size_t)h*D_;
  const int t0 = c*T_;
  const int trow = 16*w + l15;
  const unsigned short* Pb = ws + P_OFF;

  // issue q/k row loads first (latency overlaps Vt staging)
  const float* qrow = qq + gbase + (size_t)(t0 + trow)*HD_;
  const float* krow = kk + gbase + (size_t)(t0 + trow)*HD_;
  float4 q4a = *(const float4*)(qrow + quad*8);
  float4 q4b = *(const float4*)(qrow + quad*8 + 4);
  float4 q4c = *(const float4*)(qrow + 32 + quad*8);
  float4 q4d = *(const float4*)(qrow + 32 + quad*8 + 4);
  float4 k4a = *(const float4*)(krow + quad*8);
  float4 k4b = *(const float4*)(krow + quad*8 + 4);
  float4 k4c = *(const float4*)(krow + 32 + quad*8);
  float4 k4d = *(const float4*)(krow + 32 + quad*8 + 4);

  // stage Vt[d][t] (transpose, swizzled)
  for (int fi = tid; fi < 64*16; fi += 256) {
    int t = fi >> 4, d4 = (fi & 15)*4;
    float4 v4 = *(const float4*)(vv + gbase + (size_t)(t0+t)*HD_ + d4);
    Vt[SWZ64(d4+0, t)] = f2bf(v4.x);
    Vt[SWZ64(d4+1, t)] = f2bf(v4.y);
    Vt[SWZ64(d4+2, t)] = f2bf(v4.z);
    Vt[SWZ64(d4+3, t)] = f2bf(v4.w);
  }

  bf16x8 bq0 = cvt8(q4a, q4b), bq1 = cvt8(q4c, q4d);
  bf16x8 bk0 = cvt8(k4a, k4b), bk1 = cvt8(k4c, k4d);

  unsigned short* qfb = ws + QF_OFF + (size_t)(bh*C_+c)*REC_F;
  unsigned short* csb = ws + (size_t)(bh*C_+c)*REC_CS;

  // features, swapped operands: D[m][t] -> lane holds t=trow, m=16ct+4quad+reg
  bf16x4 qreg[8];
  #pragma unroll
  for (int ct = 0; ct < 8; ++ct) {
    bf16x8 ap0 = *(const bf16x8*)(Pb + (ct*16 + l15)*64 + quad*8);
    bf16x8 ap1 = *(const bf16x8*)(Pb + (ct*16 + l15)*64 + 32 + quad*8);
    f32x4 qa = {0.f,0.f,0.f,0.f}, ka = {0.f,0.f,0.f,0.f};
    qa = MFMA(ap0,bq0,qa); qa = MFMA(ap1,bq1,qa);
    ka = MFMA(ap0,bk0,ka); ka = MFMA(ap1,bk1,ka);
    union { bf16x4 v; short s[4]; } pq, pk;
    #pragma unroll
    for (int reg = 0; reg < 4; ++reg) {
      int m = 16*ct + 4*quad + reg;
      short qv = f2bf(fmaxf(qa[reg]*RATIO, 0.f) + EPS);
      short kv = f2bf(fmaxf(ka[reg]*RATIO, 0.f) + EPS);
      pq.s[reg] = qv; pk.s[reg] = kv;
      Kft[SWZ64(m, trow)] = kv;
    }
    qreg[ct] = pq.v;
    *(bf16x4*)(qfb + trow*128 + 16*ct + 4*quad) = pq.v;
    *(bf16x4*)&KfTM[SWZ128(trow, 16*ct + 4*quad)] = pk.v;
  }

  // Qf A-frags via same-wave scratch, two barrier-free half-passes.
  // pass p covers m in [64p, 64p+64): qfr[2p+ks'] = Qf[trow][64p+32ks'+8q..+7]
  bf16x8 qfr[4];
  #pragma unroll
  for (int p = 0; p < 2; ++p) {
    #pragma unroll
    for (int ct2 = 0; ct2 < 4; ++ct2)
      *(bf16x4*)&Scr[SWZ64(trow, 16*ct2 + 4*quad)] = qreg[4*p + ct2];
    qfr[2*p+0] = *(const bf16x8*)&Scr[SWZ64(trow, 8*quad)];
    qfr[2*p+1] = *(const bf16x8*)&Scr[SWZ64(trow, 32 + 8*quad)];
  }
  __syncthreads();  // Vt, Kft, KfTM complete

  // ks[m] = sum_t Kf[t][m] (row-sum of Kft)
  if (tid < 128) {
    float s = 0.f;
    #pragma unroll
    for (int i = 0; i < 8; ++i) {
      bf16x8 r = *(const bf16x8*)&Kft[SWZ64(tid, 8*i)];
      #pragma unroll
      for (int j = 0; j < 8; ++j) s += bf2f(r[j]);
    }
    csb[64*128 + tid] = (unsigned short)f2bf(s);
  }

  // KV^T: cs[d][m] = sum_t Kf[t][m] V[t][d]; D[m][d], packed 8B stores
  {
    bf16x8 av0 = *(const bf16x8*)&Vt[SWZ64(trow, 8*quad)];
    bf16x8 av1 = *(const bf16x8*)&Vt[SWZ64(trow, 32 + 8*quad)];
    #pragma unroll
    for (int mt = 0; mt < 8; ++mt) {
      bf16x8 b0 = *(const bf16x8*)&Kft[SWZ64(16*mt + l15, 8*quad)];
      bf16x8 b1 = *(const bf16x8*)&Kft[SWZ64(16*mt + l15, 32 + 8*quad)];
      f32x4 acc = {0.f,0.f,0.f,0.f};
      acc = MFMA(b0, av0, acc);
      acc = MFMA(b1, av1, acc);
      union { bf16x4 v; short s[4]; } pc;
      #pragma unroll
      for (int reg = 0; reg < 4; ++reg) pc.s[reg] = f2bf(acc[reg]);
      *(bf16x4*)(csb + trow*128 + 16*mt + 4*quad) = pc.v;
    }
  }

  // S = mask(Qf Kf^T): D[t][j], A=Qf regs, B=KfTM rows
  f32x4 sacc[4];
  #pragma unroll
  for (int jt = 0; jt < 4; ++jt) { f32x4 z = {0.f,0.f,0.f,0.f}; sacc[jt] = z; }
  #pragma unroll
  for (int ks2 = 0; ks2 < 4; ++ks2) {
    #pragma unroll
    for (int jt = 0; jt < 4; ++jt) {
      bf16x8 bb = *(const bf16x8*)&KfTM[SWZ128(16*jt + l15, 32*ks2 + 8*quad)];
      sacc[jt] = MFMA(qfr[ks2], bb, sacc[jt]);
    }
  }

  // mask + rowsum + Sm (reuse Scr; same-wave rows only -> no barrier)
  short* Sm = Scr;
  float rs[4] = {0.f,0.f,0.f,0.f};
  #pragma unroll
  for (int jt = 0; jt < 4; ++jt)
    #pragma unroll
    for (int reg = 0; reg < 4; ++reg) {
      int row = 16*w + 4*quad + reg;
      int j = l15 + 16*jt;
      float val = (j <= row) ? sacc[jt][reg] : 0.f;
      rs[reg] += val;
      Sm[SWZ64(row, j)] = f2bf(val);
    }
  #pragma unroll
  for (int reg = 0; reg < 4; ++reg) {
    rs[reg] += __shfl_xor(rs[reg], 1);
    rs[reg] += __shfl_xor(rs[reg], 2);
    rs[reg] += __shfl_xor(rs[reg], 4);
    rs[reg] += __shfl_xor(rs[reg], 8);
  }
  float* rsg = (float*)(ws + RS_OFF);
  if (l15 < 4) {
    float v = (l15==0) ? rs[0] : (l15==1) ? rs[1] : (l15==2) ? rs[2] : rs[3];
    rsg[bh*L_ + t0 + 16*w + 4*quad + l15] = v;
  }

  // num2[t][d] = S V as D[d][t]: A=Vt rows d, B=Sm rows t (same-wave)
  float* n2 = (float*)(ws + N2_OFF);
  f32x4 nacc[4];
  #pragma unroll
  for (int ct = 0; ct < 4; ++ct) { f32x4 z = {0.f,0.f,0.f,0.f}; nacc[ct] = z; }
  #pragma unroll
  for (int kss = 0; kss < 2; ++kss) {
    bf16x8 sb = *(const bf16x8*)&Sm[SWZ64(trow, 32*kss + 8*quad)];
    #pragma unroll
    for (int ct = 0; ct < 4; ++ct) {
      bf16x8 a = *(const bf16x8*)&Vt[SWZ64(16*ct + l15, 32*kss + 8*quad)];
      nacc[ct] = MFMA(a, sb, nacc[ct]);
    }
  }
  const int tg = t0 + trow;
  #pragma unroll
  for (int ct = 0; ct < 4; ++ct) {
    float4 o;
    o.x = nacc[ct][0]; o.y = nacc[ct][1]; o.z = nacc[ct][2]; o.w = nacc[ct][3];
    *(float4*)(n2 + gbase + (size_t)tg*HD_ + 16*ct + 4*quad) = o;
  }
}

// ---------------- k2: bf16 exclusive prefix, 520x64, bf16x4 prefetch --------
__global__ __launch_bounds__(64) void k2(unsigned short* __restrict__ ws)
{
  const int gid = blockIdx.x*64 + threadIdx.x;   // 520*64 = 33280 = 16*2080
  const int bh = gid / 2080, e = (gid % 2080)*4;
  unsigned short* base = ws + (size_t)bh*C_*REC_CS + e;
  bf16x4 v[64];
  #pragma unroll
  for (int c2 = 0; c2 < 64; ++c2) v[c2] = *(const bf16x4*)(base + (size_t)c2*REC_CS);
  float run[4] = {0.f,0.f,0.f,0.f};
  #pragma unroll
  for (int c2 = 0; c2 < 64; ++c2) {
    union { bf16x4 v; short s[4]; } wv;
    #pragma unroll
    for (int j = 0; j < 4; ++j) { wv.s[j] = f2bf(run[j]); run[j] += bf2f(v[c2][j]); }
    *(bf16x4*)(base + (size_t)c2*REC_CS) = wv.v;
  }
}

// ---------------- k3: num1 + combine; cs LDS-staged once --------------------
__global__ __launch_bounds__(256) void k3(
    const unsigned short* __restrict__ ws, float* __restrict__ out)
{
  __shared__ short csL[64*128];     // [d][m], SWZ128
  __shared__ float ks_lds[128];

  const int tid = threadIdx.x, bid = blockIdx.x;
  const int bh = bid >> 6, c = bid & 63;
  const int b = bh >> 3, h = bh & 7;
  const int lane = tid & 63, w = tid >> 6, quad = lane >> 4, l15 = lane & 15;
  const size_t gbase = (size_t)b*LHD_ + (size_t)h*D_;
  const int t0 = c*T_;
  const unsigned short* csb = ws + (size_t)(bh*C_+c)*REC_CS;
  const unsigned short* qfb = ws + QF_OFF + (size_t)(bh*C_+c)*REC_F;
  const float* n2 = (const float*)(ws + N2_OFF);
  const float* rsg = (const float*)(ws + RS_OFF);
  const int trow = 16*w + l15;
  const int tg = t0 + trow;

  // stage cs[d][m] (coalesced 16B reads), ks as f32
  for (int i = tid; i < 1024; i += 256) {
    int row = i >> 4, cb = (i & 15)*8;
    *(bf16x8*)&csL[SWZ128(row, cb)] = *(const bf16x8*)(csb + i*8);
  }
  if (tid < 128) ks_lds[tid] = bf2f((short)csb[64*128 + tid]);

  // hoisted global loads: n2, rs, Qf frags
  float4 nv[4];
  #pragma unroll
  for (int ct = 0; ct < 4; ++ct)
    nv[ct] = *(const float4*)(n2 + gbase + (size_t)tg*HD_ + 16*ct + 4*quad);
  float rsv = rsg[bh*L_ + tg];
  bf16x8 qfB[4];
  #pragma unroll
  for (int ks2 = 0; ks2 < 4; ++ks2)
    qfB[ks2] = *(const bf16x8*)(qfb + trow*128 + ks2*32 + quad*8);

  __syncthreads();

  // den1 = Qf . ks_prefix (per-lane partial over 32 m, reduce across quads)
  float dp = 0.f;
  #pragma unroll
  for (int ks2 = 0; ks2 < 4; ++ks2)
    #pragma unroll
    for (int j = 0; j < 8; ++j) dp += bf2f(qfB[ks2][j]) * ks_lds[ks2*32 + quad*8 + j];
  dp += __shfl_xor(dp, 16);
  dp += __shfl_xor(dp, 32);
  float inv = 1.f / (dp + rsv);

  // num1 = Qf * KVpre as D[d][t]: A=csL rows d, B=Qf rows t
  f32x4 nacc[4];
  #pragma unroll
  for (int ct = 0; ct < 4; ++ct) { f32x4 z = {0.f,0.f,0.f,0.f}; nacc[ct] = z; }
  #pragma unroll
  for (int ks2 = 0; ks2 < 4; ++ks2) {
    #pragma unroll
    for (int ct = 0; ct < 4; ++ct) {
      bf16x8 a = *(const bf16x8*)&csL[SWZ128(16*ct + l15, 32*ks2 + 8*quad)];
      nacc[ct] = MFMA(a, qfB[ks2], nacc[ct]);
    }
  }
  #pragma unroll
  for (int ct = 0; ct < 4; ++ct) {
    float4 o;
    o.x = (nacc[ct][0] + nv[ct].x) * inv;
    o.y = (nacc[ct][1] + nv[ct].y) * inv;
    o.z = (nacc[ct][2] + nv[ct].z) * inv;
    o.w = (nacc[ct][3] + nv[ct].w) * inv;
    *(float4*)(out + gbase + (size_t)tg*HD_ + 16*ct + 4*quad) = o;
  }
}

extern "C" void kernel_launch(void* const* d_in, const int* in_sizes, int n_in,
                              void* d_out, int out_size, void* d_ws, size_t ws_size,
                              hipStream_t stream) {
  const float* q = (const float*)d_in[0];
  const float* k = (const float*)d_in[1];
  const float* v = (const float*)d_in[2];
  const float* P = (const float*)d_in[3];
  float* out = (float*)d_out;
  unsigned short* ws = (unsigned short*)d_ws;  // needs ~50.9 MB

  k0<<<dim3(8),      dim3(256), 0, stream>>>(P, ws);
  k1<<<dim3(BH_*C_), dim3(256), 0, stream>>>(q, k, v, ws);
  k2<<<dim3(520),    dim3(64),  0, stream>>>(ws);
  k3<<<dim3(BH_*C_), dim3(256), 0, stream>>>(ws, out);
}

// Round 6
// 126.548 us; speedup vs baseline: 1.0986x; 1.0146x over previous
//
#include <hip/hip_runtime.h>

// FAVOR+ causal linear attention, fp32 I/O, bf16 MFMA chunked-GEMM form.
// B=2, L=4096, H=8, D=64, M=128, chunks C=64 x T=64.
// R5 (resubmit; prior bench was a container/infra failure, no kernel signal):
// k1 LDS trimmed to EXACTLY 40KB -> 4 blocks/CU -> grid 1024 fits in ONE
// residency round (R4's 48KB gave 3/CU = 768 capacity -> 1.33 rounds, the
// straggler round ran at 1/3 occupancy and ate the gain).
//   k0: P fp32 -> bf16 once.
//   k1: features Qf,Kf; cs = (V^T Kf, colsum Kf); S = mask(Qf Kf^T);
//       num2 = S V -> n2 (f32); rs = rowsum(S).
//       Qf A-frags via in-wave 64-bit shuffles (Scr buffer eliminated);
//       Sm reuses Kft after barrier 2 (Kft dead post ks/KV^T).
//   k2: exclusive bf16 prefix; 520 blocks x 64 thr, bf16x4 full prefetch.
//   k3: num1 = Qf*KVpre + combine; cs LDS-staged once.

#define B_ 2
#define L_ 4096
#define H_ 8
#define D_ 64
#define M_ 128
#define BH_ 16
#define HD_ 512
#define LHD_ (L_*HD_)
#define C_ 64
#define T_ 64
#define RATIO 0.08838834764831845f
#define EPS 1e-3f

#define REC_CS 8320                    // shorts per cs record: 64*128 KVt + 128 ks
#define REC_F  8192                    // shorts per Qf record: 64*128
#define QF_OFF 8519680                 // shorts: 16*64*8320
#define N2_OFF 16908288                // shorts: QF_OFF + 16*64*8192 (f32 region)
#define RS_OFF 25296896                // shorts: N2_OFF + 2*4194304   (f32 region)
#define P_OFF  25427968                // shorts: RS_OFF + 131072; P bf16 [m][d]

// XOR-swizzles (bank-conflict-free, keep 8-short groups contiguous):
#define SWZ64(r,c)  ((r)*64  + ((c) ^ (((r)&7)*8)))
#define SWZ128(r,c) ((r)*128 + ((c) ^ (((r)&15)*8)))

typedef __attribute__((ext_vector_type(8))) short bf16x8;
typedef __attribute__((ext_vector_type(4))) short bf16x4;
typedef __attribute__((ext_vector_type(4))) float f32x4;

__device__ __forceinline__ short f2bf(float f) {
  union { float f; unsigned u; } x; x.f = f;
  unsigned r = (x.u + 0x7fffu + ((x.u >> 16) & 1u)) >> 16;
  return (short)r;
}
__device__ __forceinline__ float bf2f(short s) {
  union { unsigned u; float f; } x; x.u = ((unsigned)(unsigned short)s) << 16;
  return x.f;
}
__device__ __forceinline__ bf16x8 cvt8(float4 a, float4 b) {
  union { bf16x8 v; short s[8]; } u;
  u.s[0]=f2bf(a.x); u.s[1]=f2bf(a.y); u.s[2]=f2bf(a.z); u.s[3]=f2bf(a.w);
  u.s[4]=f2bf(b.x); u.s[5]=f2bf(b.y); u.s[6]=f2bf(b.z); u.s[7]=f2bf(b.w);
  return u.v;
}
#define MFMA(a,b,c) __builtin_amdgcn_mfma_f32_16x16x32_bf16((a),(b),(c),0,0,0)

// ---------------- k0: P -> bf16 once ----------------------------------------
__global__ __launch_bounds__(256) void k0(
    const float* __restrict__ P, unsigned short* __restrict__ ws)
{
  const int i = (blockIdx.x*256 + threadIdx.x)*4;   // 8 blocks * 256 * 4 = 8192
  float4 p4 = *(const float4*)(P + i);
  union { bf16x4 v; short s[4]; } u;
  u.s[0]=f2bf(p4.x); u.s[1]=f2bf(p4.y); u.s[2]=f2bf(p4.z); u.s[3]=f2bf(p4.w);
  *(bf16x4*)(ws + P_OFF + i) = u.v;
}

// ---------------- k1: all intra-chunk work (40KB LDS, 4 blocks/CU) ----------
__global__ __launch_bounds__(256) void k1(
    const float* __restrict__ qq, const float* __restrict__ kk,
    const float* __restrict__ vv, unsigned short* __restrict__ ws)
{
  __shared__ short Vt[64*64];        // [d][t], SWZ64 (8KB)
  __shared__ short Kft[128*64];      // [m][t], SWZ64 (16KB); rows 0-63 -> Sm later
  __shared__ short KfTM[64*128];     // [t][m], SWZ128 (16KB)

  const int tid = threadIdx.x, bid = blockIdx.x;
  const int bh = bid >> 6, c = bid & 63;
  const int b = bh >> 3, h = bh & 7;
  const int lane = tid & 63, w = tid >> 6, quad = lane >> 4, l15 = lane & 15;
  const size_t gbase = (size_t)b*LHD_ + (size_t)h*D_;
  const int t0 = c*T_;
  const int trow = 16*w + l15;
  const unsigned short* Pb = ws + P_OFF;

  // issue q/k row loads first (latency overlaps Vt staging)
  const float* qrow = qq + gbase + (size_t)(t0 + trow)*HD_;
  const float* krow = kk + gbase + (size_t)(t0 + trow)*HD_;
  float4 q4a = *(const float4*)(qrow + quad*8);
  float4 q4b = *(const float4*)(qrow + quad*8 + 4);
  float4 q4c = *(const float4*)(qrow + 32 + quad*8);
  float4 q4d = *(const float4*)(qrow + 32 + quad*8 + 4);
  float4 k4a = *(const float4*)(krow + quad*8);
  float4 k4b = *(const float4*)(krow + quad*8 + 4);
  float4 k4c = *(const float4*)(krow + 32 + quad*8);
  float4 k4d = *(const float4*)(krow + 32 + quad*8 + 4);

  // stage Vt[d][t] (transpose, swizzled)
  for (int fi = tid; fi < 64*16; fi += 256) {
    int t = fi >> 4, d4 = (fi & 15)*4;
    float4 v4 = *(const float4*)(vv + gbase + (size_t)(t0+t)*HD_ + d4);
    Vt[SWZ64(d4+0, t)] = f2bf(v4.x);
    Vt[SWZ64(d4+1, t)] = f2bf(v4.y);
    Vt[SWZ64(d4+2, t)] = f2bf(v4.z);
    Vt[SWZ64(d4+3, t)] = f2bf(v4.w);
  }

  bf16x8 bq0 = cvt8(q4a, q4b), bq1 = cvt8(q4c, q4d);
  bf16x8 bk0 = cvt8(k4a, k4b), bk1 = cvt8(k4c, k4d);

  unsigned short* qfb = ws + QF_OFF + (size_t)(bh*C_+c)*REC_F;
  unsigned short* csb = ws + (size_t)(bh*C_+c)*REC_CS;

  // features, swapped operands: D[m][t] -> lane holds t=trow, m=16ct+4quad+reg
  bf16x4 qreg[8];
  #pragma unroll
  for (int ct = 0; ct < 8; ++ct) {
    bf16x8 ap0 = *(const bf16x8*)(Pb + (ct*16 + l15)*64 + quad*8);
    bf16x8 ap1 = *(const bf16x8*)(Pb + (ct*16 + l15)*64 + 32 + quad*8);
    f32x4 qa = {0.f,0.f,0.f,0.f}, ka = {0.f,0.f,0.f,0.f};
    qa = MFMA(ap0,bq0,qa); qa = MFMA(ap1,bq1,qa);
    ka = MFMA(ap0,bk0,ka); ka = MFMA(ap1,bk1,ka);
    union { bf16x4 v; short s[4]; } pq, pk;
    #pragma unroll
    for (int reg = 0; reg < 4; ++reg) {
      int m = 16*ct + 4*quad + reg;
      short qv = f2bf(fmaxf(qa[reg]*RATIO, 0.f) + EPS);
      short kv = f2bf(fmaxf(ka[reg]*RATIO, 0.f) + EPS);
      pq.s[reg] = qv; pk.s[reg] = kv;
      Kft[SWZ64(m, trow)] = kv;
    }
    qreg[ct] = pq.v;
    *(bf16x4*)(qfb + trow*128 + 16*ct + 4*quad) = pq.v;
    *(bf16x4*)&KfTM[SWZ128(trow, 16*ct + 4*quad)] = pk.v;
  }

  // Qf A-frags via in-wave shuffles (no LDS):
  // dest lane (q,l15) wants Qf[trow][32ks2+8q .. +7]:
  //   lo half from lane (2(q&1))*16+l15, reg qreg[2ks2+(q>>1)]
  //   hi half from lane (2(q&1)+1)*16+l15, same reg
  bf16x8 qfr[4];
  {
    const int src_lo = (2*(quad & 1))*16 + l15;
    #pragma unroll
    for (int ks2 = 0; ks2 < 4; ++ks2) {
      union { bf16x4 v; long long l; } a0, a1;
      a0.v = qreg[2*ks2]; a1.v = qreg[2*ks2+1];
      long long loA = __shfl(a0.l, src_lo, 64);
      long long hiA = __shfl(a0.l, src_lo + 16, 64);
      long long loB = __shfl(a1.l, src_lo, 64);
      long long hiB = __shfl(a1.l, src_lo + 16, 64);
      union { bf16x8 v8; long long l[2]; } r;
      r.l[0] = (quad < 2) ? loA : loB;
      r.l[1] = (quad < 2) ? hiA : hiB;
      qfr[ks2] = r.v8;
    }
  }
  __syncthreads();  // sync1: Vt, Kft, KfTM complete

  // ks[m] = sum_t Kf[t][m] (row-sum of Kft)
  if (tid < 128) {
    float s = 0.f;
    #pragma unroll
    for (int i = 0; i < 8; ++i) {
      bf16x8 r = *(const bf16x8*)&Kft[SWZ64(tid, 8*i)];
      #pragma unroll
      for (int j = 0; j < 8; ++j) s += bf2f(r[j]);
    }
    csb[64*128 + tid] = (unsigned short)f2bf(s);
  }

  // KV^T: cs[d][m] = sum_t Kf[t][m] V[t][d]; D[m][d], packed 8B stores
  {
    bf16x8 av0 = *(const bf16x8*)&Vt[SWZ64(trow, 8*quad)];
    bf16x8 av1 = *(const bf16x8*)&Vt[SWZ64(trow, 32 + 8*quad)];
    #pragma unroll
    for (int mt = 0; mt < 8; ++mt) {
      bf16x8 b0 = *(const bf16x8*)&Kft[SWZ64(16*mt + l15, 8*quad)];
      bf16x8 b1 = *(const bf16x8*)&Kft[SWZ64(16*mt + l15, 32 + 8*quad)];
      f32x4 acc = {0.f,0.f,0.f,0.f};
      acc = MFMA(b0, av0, acc);
      acc = MFMA(b1, av1, acc);
      union { bf16x4 v; short s[4]; } pc;
      #pragma unroll
      for (int reg = 0; reg < 4; ++reg) pc.s[reg] = f2bf(acc[reg]);
      *(bf16x4*)(csb + trow*128 + 16*mt + 4*quad) = pc.v;
    }
  }

  // S = mask(Qf Kf^T): D[t][j], A=Qf shuffled regs, B=KfTM rows
  f32x4 sacc[4];
  #pragma unroll
  for (int jt = 0; jt < 4; ++jt) { f32x4 z = {0.f,0.f,0.f,0.f}; sacc[jt] = z; }
  #pragma unroll
  for (int ks2 = 0; ks2 < 4; ++ks2) {
    #pragma unroll
    for (int jt = 0; jt < 4; ++jt) {
      bf16x8 bb = *(const bf16x8*)&KfTM[SWZ128(16*jt + l15, 32*ks2 + 8*quad)];
      sacc[jt] = MFMA(qfr[ks2], bb, sacc[jt]);
    }
  }
  __syncthreads();  // sync2: all Kft/KfTM reads done -> Kft rows 0-63 reusable

  // mask + rowsum + Sm (reuse Kft; same-wave rows only -> no further barrier)
  short* Sm = Kft;
  float rs[4] = {0.f,0.f,0.f,0.f};
  #pragma unroll
  for (int jt = 0; jt < 4; ++jt)
    #pragma unroll
    for (int reg = 0; reg < 4; ++reg) {
      int row = 16*w + 4*quad + reg;
      int j = l15 + 16*jt;
      float val = (j <= row) ? sacc[jt][reg] : 0.f;
      rs[reg] += val;
      Sm[SWZ64(row, j)] = f2bf(val);
    }
  #pragma unroll
  for (int reg = 0; reg < 4; ++reg) {
    rs[reg] += __shfl_xor(rs[reg], 1);
    rs[reg] += __shfl_xor(rs[reg], 2);
    rs[reg] += __shfl_xor(rs[reg], 4);
    rs[reg] += __shfl_xor(rs[reg], 8);
  }
  float* rsg = (float*)(ws + RS_OFF);
  if (l15 < 4) {
    float v = (l15==0) ? rs[0] : (l15==1) ? rs[1] : (l15==2) ? rs[2] : rs[3];
    rsg[bh*L_ + t0 + 16*w + 4*quad + l15] = v;
  }

  // num2[t][d] = S V as D[d][t]: A=Vt rows d, B=Sm rows t (same-wave)
  float* n2 = (float*)(ws + N2_OFF);
  f32x4 nacc[4];
  #pragma unroll
  for (int ct = 0; ct < 4; ++ct) { f32x4 z = {0.f,0.f,0.f,0.f}; nacc[ct] = z; }
  #pragma unroll
  for (int kss = 0; kss < 2; ++kss) {
    bf16x8 sb = *(const bf16x8*)&Sm[SWZ64(trow, 32*kss + 8*quad)];
    #pragma unroll
    for (int ct = 0; ct < 4; ++ct) {
      bf16x8 a = *(const bf16x8*)&Vt[SWZ64(16*ct + l15, 32*kss + 8*quad)];
      nacc[ct] = MFMA(a, sb, nacc[ct]);
    }
  }
  const int tg = t0 + trow;
  #pragma unroll
  for (int ct = 0; ct < 4; ++ct) {
    float4 o;
    o.x = nacc[ct][0]; o.y = nacc[ct][1]; o.z = nacc[ct][2]; o.w = nacc[ct][3];
    *(float4*)(n2 + gbase + (size_t)tg*HD_ + 16*ct + 4*quad) = o;
  }
}

// ---------------- k2: bf16 exclusive prefix, 520x64, bf16x4 prefetch --------
__global__ __launch_bounds__(64) void k2(unsigned short* __restrict__ ws)
{
  const int gid = blockIdx.x*64 + threadIdx.x;   // 520*64 = 33280 = 16*2080
  const int bh = gid / 2080, e = (gid % 2080)*4;
  unsigned short* base = ws + (size_t)bh*C_*REC_CS + e;
  bf16x4 v[64];
  #pragma unroll
  for (int c2 = 0; c2 < 64; ++c2) v[c2] = *(const bf16x4*)(base + (size_t)c2*REC_CS);
  float run[4] = {0.f,0.f,0.f,0.f};
  #pragma unroll
  for (int c2 = 0; c2 < 64; ++c2) {
    union { bf16x4 v; short s[4]; } wv;
    #pragma unroll
    for (int j = 0; j < 4; ++j) { wv.s[j] = f2bf(run[j]); run[j] += bf2f(v[c2][j]); }
    *(bf16x4*)(base + (size_t)c2*REC_CS) = wv.v;
  }
}

// ---------------- k3: num1 + combine; cs LDS-staged once --------------------
__global__ __launch_bounds__(256) void k3(
    const unsigned short* __restrict__ ws, float* __restrict__ out)
{
  __shared__ short csL[64*128];     // [d][m], SWZ128
  __shared__ float ks_lds[128];

  const int tid = threadIdx.x, bid = blockIdx.x;
  const int bh = bid >> 6, c = bid & 63;
  const int b = bh >> 3, h = bh & 7;
  const int lane = tid & 63, w = tid >> 6, quad = lane >> 4, l15 = lane & 15;
  const size_t gbase = (size_t)b*LHD_ + (size_t)h*D_;
  const int t0 = c*T_;
  const unsigned short* csb = ws + (size_t)(bh*C_+c)*REC_CS;
  const unsigned short* qfb = ws + QF_OFF + (size_t)(bh*C_+c)*REC_F;
  const float* n2 = (const float*)(ws + N2_OFF);
  const float* rsg = (const float*)(ws + RS_OFF);
  const int trow = 16*w + l15;
  const int tg = t0 + trow;

  // stage cs[d][m] (coalesced 16B reads), ks as f32
  for (int i = tid; i < 1024; i += 256) {
    int row = i >> 4, cb = (i & 15)*8;
    *(bf16x8*)&csL[SWZ128(row, cb)] = *(const bf16x8*)(csb + i*8);
  }
  if (tid < 128) ks_lds[tid] = bf2f((short)csb[64*128 + tid]);

  // hoisted global loads: n2, rs, Qf frags
  float4 nv[4];
  #pragma unroll
  for (int ct = 0; ct < 4; ++ct)
    nv[ct] = *(const float4*)(n2 + gbase + (size_t)tg*HD_ + 16*ct + 4*quad);
  float rsv = rsg[bh*L_ + tg];
  bf16x8 qfB[4];
  #pragma unroll
  for (int ks2 = 0; ks2 < 4; ++ks2)
    qfB[ks2] = *(const bf16x8*)(qfb + trow*128 + ks2*32 + quad*8);

  __syncthreads();

  // den1 = Qf . ks_prefix (per-lane partial over 32 m, reduce across quads)
  float dp = 0.f;
  #pragma unroll
  for (int ks2 = 0; ks2 < 4; ++ks2)
    #pragma unroll
    for (int j = 0; j < 8; ++j) dp += bf2f(qfB[ks2][j]) * ks_lds[ks2*32 + quad*8 + j];
  dp += __shfl_xor(dp, 16);
  dp += __shfl_xor(dp, 32);
  float inv = 1.f / (dp + rsv);

  // num1 = Qf * KVpre as D[d][t]: A=csL rows d, B=Qf rows t
  f32x4 nacc[4];
  #pragma unroll
  for (int ct = 0; ct < 4; ++ct) { f32x4 z = {0.f,0.f,0.f,0.f}; nacc[ct] = z; }
  #pragma unroll
  for (int ks2 = 0; ks2 < 4; ++ks2) {
    #pragma unroll
    for (int ct = 0; ct < 4; ++ct) {
      bf16x8 a = *(const bf16x8*)&csL[SWZ128(16*ct + l15, 32*ks2 + 8*quad)];
      nacc[ct] = MFMA(a, qfB[ks2], nacc[ct]);
    }
  }
  #pragma unroll
  for (int ct = 0; ct < 4; ++ct) {
    float4 o;
    o.x = (nacc[ct][0] + nv[ct].x) * inv;
    o.y = (nacc[ct][1] + nv[ct].y) * inv;
    o.z = (nacc[ct][2] + nv[ct].z) * inv;
    o.w = (nacc[ct][3] + nv[ct].w) * inv;
    *(float4*)(out + gbase + (size_t)tg*HD_ + 16*ct + 4*quad) = o;
  }
}

extern "C" void kernel_launch(void* const* d_in, const int* in_sizes, int n_in,
                              void* d_out, int out_size, void* d_ws, size_t ws_size,
                              hipStream_t stream) {
  const float* q = (const float*)d_in[0];
  const float* k = (const float*)d_in[1];
  const float* v = (const float*)d_in[2];
  const float* P = (const float*)d_in[3];
  float* out = (float*)d_out;
  unsigned short* ws = (unsigned short*)d_ws;  // needs ~50.9 MB

  k0<<<dim3(8),      dim3(256), 0, stream>>>(P, ws);
  k1<<<dim3(BH_*C_), dim3(256), 0, stream>>>(q, k, v, ws);
  k2<<<dim3(520),    dim3(64),  0, stream>>>(ws);
  k3<<<dim3(BH_*C_), dim3(256), 0, stream>>>(ws, out);
}